// Round 2
// 98.582 us; speedup vs baseline: 1.0695x; 1.0695x over previous
//
#include <hip/hip_runtime.h>

// Problem constants: N1=N2=512, C=256, H=512. Inputs/outputs fp32.
// M[i,j] = b2 + sum_h relu(hx[i,h] + hy[j,h] + b1[h]) * w2[h]
//   hx = (X @ W_sr.T) @ W1x.T, hy = (Y @ W_tg.T) @ W1y.T + b1.
//
// All stages move f16 data and accumulate fp32 via v_dot2_f32_f16.
// R3 lesson: grid.sync ~35us on gfx950 -- separate launches are cheaper.
// R1 lesson: cap unrolls (full unroll -> 256 VGPR + scratch spills).
// R5 lesson (cycle accounting): both GEMMs were LDS-pipe-bound; balance
// reads vs dot2 with bigger per-thread tiles + 1 block/CU grids.
// R6: pipeline is serialization-bound, not pipe-bound.
//   (a) reduce8 eliminated: gemm1 pre-fills out with b2, core atomicAdds
//       f32 partials directly (-1 launch, -9MB traffic, better accuracy).
//   (b) GEMM staging is register double-buffered: next K-tile's global
//       loads issue before current tile's compute (2 waves/CU cannot hide
//       latency via TLP -- must use ILP).
// R7: R6 bench died on container-infra ("failed twice", no pytest/counters)
//   -- resubmitting R6 unchanged to get a clean measurement before mutating.

typedef _Float16 h2 __attribute__((ext_vector_type(2)));
typedef _Float16 h4 __attribute__((ext_vector_type(4)));
typedef _Float16 h8 __attribute__((ext_vector_type(8)));

// ---------------------------------------------------------------------------
// GEMM-NT stage 1: Xp = X @ W_sr.T (and Y-path), f32 inputs converted to f16
// at staging, dot2 compute, f16 out. M=512, N=256, K=256, lda=ldb=256.
// BM=32, BN=32, BK=32. 128 threads, per-thread 4 rows x 2 cols.
// LDS pair-major [kp][2m], stride 72 halfs (144 B, 16B-aligned rows).
// Also pre-fills out (512x512 f32) with b2 for the core's atomic epilogue.
// ---------------------------------------------------------------------------
__global__ __launch_bounds__(128) void gemm1_f16(
    const float* __restrict__ A0, const float* __restrict__ A1,
    const float* __restrict__ B0, const float* __restrict__ B1,
    _Float16* __restrict__ C0, _Float16* __restrict__ C1,
    const float* __restrict__ b2, float* __restrict__ out)
{
    const int z = blockIdx.z;
    const float* A = z ? A1 : A0;
    const float* B = z ? B1 : B0;
    _Float16* Cc   = z ? C1 : C0;

    __shared__ _Float16 As2[16 * 72];   // [kp][2m], 64 halfs used/row
    __shared__ _Float16 Bs2[16 * 72];   // [kp][2n]

    const int t  = threadIdx.x;
    const int m0 = blockIdx.x * 32;
    const int n0 = blockIdx.y * 32;
    const int ti = t >> 4;   // 0..7  -> rows 4ti..4ti+3
    const int tj = t & 15;   // 0..15 -> cols 2tj..2tj+1

    // out <- b2 (1024 floats per block; 8 per thread). Stream-ordered
    // before affinity_core's atomicAdd epilogue; re-runs on every graph
    // replay so the accumulation stays idempotent.
    {
        const int bid = blockIdx.x + 16 * (blockIdx.y + 8 * blockIdx.z);
        const float bb = b2[0];
        float4 f = {bb, bb, bb, bb};
        float* o = out + bid * 1024 + t * 8;
        *(float4*)o = f;
        *(float4*)(o + 4) = f;
    }

    float acc[4][2] = {};

    // Prefetch kt=0 tile into registers.
    float4 va[2], vb[2];
    #pragma unroll
    for (int r = 0; r < 2; r++) {
        const int id = t + r * 128;
        va[r] = *(const float4*)&A[(m0 + (id >> 3)) * 256 + (id & 7) * 4];
        vb[r] = *(const float4*)&B[(n0 + (id >> 3)) * 256 + (id & 7) * 4];
    }

    for (int kt = 0; kt < 256; kt += 32) {
        // Stage current tile regs -> LDS (f32 -> f16 pair-major)
        #pragma unroll
        for (int r = 0; r < 2; r++) {
            const int id  = t + r * 128;
            const int m   = id >> 3;
            const int k4  = (id & 7) * 4;
            const int kp0 = k4 >> 1;
            h2 alo = {(_Float16)va[r].x, (_Float16)va[r].y};
            h2 ahi = {(_Float16)va[r].z, (_Float16)va[r].w};
            *(h2*)&As2[kp0 * 72 + 2 * m]       = alo;
            *(h2*)&As2[(kp0 + 1) * 72 + 2 * m] = ahi;
            h2 blo = {(_Float16)vb[r].x, (_Float16)vb[r].y};
            h2 bhi = {(_Float16)vb[r].z, (_Float16)vb[r].w};
            *(h2*)&Bs2[kp0 * 72 + 2 * m]       = blo;
            *(h2*)&Bs2[(kp0 + 1) * 72 + 2 * m] = bhi;
        }
        __syncthreads();

        // Issue next tile's global loads NOW; latency hides under compute.
        if (kt < 224) {
            #pragma unroll
            for (int r = 0; r < 2; r++) {
                const int id = t + r * 128;
                va[r] = *(const float4*)&A[(m0 + (id >> 3)) * 256 + kt + 32 + (id & 7) * 4];
                vb[r] = *(const float4*)&B[(n0 + (id >> 3)) * 256 + kt + 32 + (id & 7) * 4];
            }
        }

        #pragma unroll 8
        for (int kp = 0; kp < 16; kp++) {
            h8 a = *(const h8*)&As2[kp * 72 + 8 * ti];   // rows 4ti..4ti+3
            h4 b = *(const h4*)&Bs2[kp * 72 + 4 * tj];   // cols 2tj..2tj+1
            const h2* ap = (const h2*)&a;
            const h2* bp = (const h2*)&b;
            #pragma unroll
            for (int mi = 0; mi < 4; mi++)
                #pragma unroll
                for (int nj = 0; nj < 2; nj++)
                    acc[mi][nj] = __builtin_amdgcn_fdot2(ap[mi], bp[nj],
                                                         acc[mi][nj], false);
        }
        __syncthreads();
    }

    #pragma unroll
    for (int mi = 0; mi < 4; mi++) {
        const int m = m0 + 4 * ti + mi;
        h2 r = {(_Float16)acc[mi][0], (_Float16)acc[mi][1]};
        *(h2*)&Cc[m * 256 + n0 + 2 * tj] = r;
    }
}

// ---------------------------------------------------------------------------
// GEMM-NT stage 2: hx = Xp @ W1x.T (+bias on y-path). A f16 (lda=256),
// B f32 (ldb=512, col offset prob*256) converted at staging. M=512, N=512.
// BM=32, BN=64, BK=32. 128 threads, per-thread 4x4.
// As2 stride 72 halfs, Bs2 stride 136 halfs (272 B, 16B-aligned rows).
// Register double-buffered staging (same rationale as gemm1).
// ---------------------------------------------------------------------------
__global__ __launch_bounds__(128) void gemm2_f16(
    const _Float16* __restrict__ A0, const _Float16* __restrict__ A1,
    const float* __restrict__ B0, const float* __restrict__ B1,
    _Float16* __restrict__ C0, _Float16* __restrict__ C1,
    const float* __restrict__ bias1)
{
    const int z = blockIdx.z;
    const _Float16* A = z ? A1 : A0;
    const float* B    = z ? B1 : B0;
    _Float16* Cc      = z ? C1 : C0;
    const float* bias = z ? bias1 : nullptr;

    __shared__ _Float16 As2[16 * 72];    // [kp][2m], 64 halfs used
    __shared__ _Float16 Bs2[16 * 136];   // [kp][2n], 128 halfs used

    const int t  = threadIdx.x;
    const int m0 = blockIdx.x * 32;
    const int n0 = blockIdx.y * 64;
    const int ti = t >> 4;   // 0..7  -> rows 4ti..4ti+3
    const int tj = t & 15;   // 0..15 -> cols 4tj..4tj+3

    float acc[4][4] = {};

    // Prefetch kt=0 tile into registers.
    h8 va;
    float4 vb[4];
    {
        const int m  = t >> 2;
        const int k8 = (t & 3) * 8;
        va = *(const h8*)&A[(m0 + m) * 256 + k8];
    }
    #pragma unroll
    for (int r = 0; r < 4; r++) {
        const int id = t + r * 128;
        vb[r] = *(const float4*)&B[(n0 + (id >> 3)) * 512 + (id & 7) * 4];
    }

    for (int kt = 0; kt < 256; kt += 32) {
        // Stage A: regs -> pair-major LDS
        {
            const int m   = t >> 2;
            const int k8  = (t & 3) * 8;
            const int kp0 = k8 >> 1;
            #pragma unroll
            for (int i = 0; i < 4; i++) {
                h2 p = {va[2 * i], va[2 * i + 1]};
                *(h2*)&As2[(kp0 + i) * 72 + 2 * m] = p;
            }
        }
        // Stage B: regs (f32) -> f16 pair-major LDS
        #pragma unroll
        for (int r = 0; r < 4; r++) {
            const int id  = t + r * 128;
            const int n   = id >> 3;
            const int k4  = (id & 7) * 4;
            const int kp0 = k4 >> 1;
            h2 lo = {(_Float16)vb[r].x, (_Float16)vb[r].y};
            h2 hi = {(_Float16)vb[r].z, (_Float16)vb[r].w};
            *(h2*)&Bs2[kp0 * 136 + 2 * n]       = lo;
            *(h2*)&Bs2[(kp0 + 1) * 136 + 2 * n] = hi;
        }
        __syncthreads();

        // Issue next tile's global loads before compute.
        if (kt < 224) {
            const int m  = t >> 2;
            const int k8 = (t & 3) * 8;
            va = *(const h8*)&A[(m0 + m) * 256 + kt + 32 + k8];
            #pragma unroll
            for (int r = 0; r < 4; r++) {
                const int id = t + r * 128;
                vb[r] = *(const float4*)&B[(n0 + (id >> 3)) * 512 + kt + 32 + (id & 7) * 4];
            }
        }

        #pragma unroll 8
        for (int kp = 0; kp < 16; kp++) {
            h8 a = *(const h8*)&As2[kp * 72 + 8 * ti];
            h8 b = *(const h8*)&Bs2[kp * 136 + 8 * tj];
            const h2* ap = (const h2*)&a;
            const h2* bp = (const h2*)&b;
            #pragma unroll
            for (int mi = 0; mi < 4; mi++)
                #pragma unroll
                for (int nj = 0; nj < 4; nj++)
                    acc[mi][nj] = __builtin_amdgcn_fdot2(ap[mi], bp[nj],
                                                         acc[mi][nj], false);
        }
        __syncthreads();
    }

    float4 bv = {0.f, 0.f, 0.f, 0.f};
    if (bias) bv = *(const float4*)&bias[n0 + 4 * tj];
    #pragma unroll
    for (int mi = 0; mi < 4; mi++) {
        const int m = m0 + 4 * ti + mi;
        h4 r = {(_Float16)(acc[mi][0] + bv.x), (_Float16)(acc[mi][1] + bv.y),
                (_Float16)(acc[mi][2] + bv.z), (_Float16)(acc[mi][3] + bv.w)};
        *(h4*)&Cc[m * 512 + n0 + 4 * tj] = r;
    }
}

// ---------------------------------------------------------------------------
// Core: out[i,j] += sum_{h in 64-slab s} relu(hx[i,h]+hy[j,h])*w2[h]
// grid (8,8,8) = 512 blocks (2/CU), 256 threads, 4x4 register tile.
// f16 operands, v_dot2_f32_f16 accumulate. f32 atomicAdd epilogue into
// out (pre-filled with b2 by gemm1) -- replaces the old partial+reduce8.
// (proven R4/R5 body -- LDS ~6.9K cy vs VALU ~6.1K cy per CU, balanced)
// ---------------------------------------------------------------------------
__global__ __launch_bounds__(256) void affinity_core(
    const _Float16* __restrict__ hx, const _Float16* __restrict__ hy,
    const float* __restrict__ w2, float* __restrict__ out)
{
    __shared__ __align__(16) _Float16 xs[64 * 72];
    __shared__ __align__(16) _Float16 ys[64 * 72];
    __shared__ __align__(16) _Float16 ws2[64];

    const int t  = threadIdx.x;
    const int i0 = blockIdx.x * 64;
    const int j0 = blockIdx.y * 64;
    const int h0 = blockIdx.z * 64;
    const int ti = t / 16;
    const int tj = t % 16;

    #pragma unroll
    for (int s = 0; s < 2; s++) {
        const int id = t + s * 256;
        const int r  = id >> 3;
        const int c8 = (id & 7) * 8;
        *(float4*)&xs[r * 72 + c8] = *(const float4*)&hx[(i0 + r) * 512 + h0 + c8];
        *(float4*)&ys[r * 72 + c8] = *(const float4*)&hy[(j0 + r) * 512 + h0 + c8];
    }
    if (t < 64) ws2[t] = (_Float16)w2[h0 + t];
    __syncthreads();

    float acc[4][4] = {};
    const _Float16* xr = xs + ti * 72;
    const _Float16* yr = ys + tj * 72;
    const h2 hz = {(_Float16)0.f, (_Float16)0.f};

    #pragma unroll 2
    for (int g = 0; g < 8; g++) {
        const int ho = g * 8;
        h8 w = *(const h8*)&ws2[ho];
        h8 x[4], y[4];
        #pragma unroll
        for (int m = 0; m < 4; m++) x[m] = *(const h8*)&xr[m * (16 * 72) + ho];
        #pragma unroll
        for (int n = 0; n < 4; n++) y[n] = *(const h8*)&yr[n * (16 * 72) + ho];
        const h2* wp = (const h2*)&w;
        #pragma unroll
        for (int m = 0; m < 4; m++) {
            const h2* xp = (const h2*)&x[m];
            #pragma unroll
            for (int n = 0; n < 4; n++) {
                const h2* yp = (const h2*)&y[n];
                float a = acc[m][n];
                #pragma unroll
                for (int p = 0; p < 4; p++) {
                    h2 s = xp[p] + yp[p];                           // v_pk_add_f16
                    s = __builtin_elementwise_max(s, hz);           // v_pk_max_f16
                    a = __builtin_amdgcn_fdot2(s, wp[p], a, false); // v_dot2_f32_f16
                }
                acc[m][n] = a;
            }
        }
    }

    // Atomic f32 epilogue: 8-way contention per address (one per h-slab),
    // 2M atomics total -- well within L2 atomic throughput.
    #pragma unroll
    for (int m = 0; m < 4; m++) {
        #pragma unroll
        for (int n = 0; n < 4; n++) {
            atomicAdd(&out[(i0 + ti + 16 * m) * 512 + (j0 + tj + 16 * n)],
                      acc[m][n]);
        }
    }
}

extern "C" void kernel_launch(void* const* d_in, const int* in_sizes, int n_in,
                              void* d_out, int out_size, void* d_ws, size_t ws_size,
                              hipStream_t stream) {
    const float* X    = (const float*)d_in[0];  // 512x256
    const float* Y    = (const float*)d_in[1];  // 512x256
    const float* W_sr = (const float*)d_in[2];  // 256x256
    const float* W_tg = (const float*)d_in[3];  // 256x256
    const float* W1   = (const float*)d_in[4];  // 512x512 (H x 2C)
    const float* b1   = (const float*)d_in[5];  // 512
    const float* w2   = (const float*)d_in[6];  // 1x512
    const float* b2   = (const float*)d_in[7];  // 1

    float* ws = (float*)d_ws;
    _Float16* Xp = (_Float16*)ws;               // 512x256 f16
    _Float16* Yp = (_Float16*)(ws + 65536);     // 512x256 f16
    _Float16* hx = (_Float16*)(ws + 131072);    // 512x512 f16
    _Float16* hy = (_Float16*)(ws + 262144);    // 512x512 f16
    float* out = (float*)d_out;

    // Stage 1: Xp = X @ W_sr.T ; Yp = Y @ W_tg.T ; out <- b2
    gemm1_f16<<<dim3(16, 8, 2), 128, 0, stream>>>(
        X, Y, W_sr, W_tg, Xp, Yp, b2, out);
    // Stage 2: hx = Xp @ W1x.T ; hy = Yp @ W1y.T + b1
    gemm2_f16<<<dim3(16, 8, 2), 128, 0, stream>>>(
        Xp, Yp, W1, W1 + 256, hx, hy, b1);
    // Stage 3: h-split relu reduction, atomic f32 accumulate into out
    affinity_core<<<dim3(8, 8, 8), 256, 0, stream>>>(hx, hy, w2, out);
}

// Round 3
// 94.947 us; speedup vs baseline: 1.1104x; 1.0383x over previous
//
#include <hip/hip_runtime.h>

// Problem constants: N1=N2=512, C=256, H=512. Inputs/outputs fp32.
// M[i,j] = b2 + sum_h relu(hx[i,h] + hy[j,h] + b1[h]) * w2[h]
//   hx = (X @ W_sr.T) @ W1x.T, hy = (Y @ W_tg.T) @ W1y.T + b1.
//
// All stages move f16 data and accumulate fp32 via v_dot2_f32_f16.
// R3 lesson: grid.sync ~35us on gfx950 -- separate launches are cheaper.
// R1 lesson: cap unrolls (full unroll -> 256 VGPR + scratch spills).
// R5 lesson (cycle accounting): both GEMMs were LDS-pipe-bound; balance
// reads vs dot2 with bigger per-thread tiles + 1 block/CU grids.
// R6: serialization-bound fixes: reduce8 folded into an atomicAdd epilogue
//   (gemm1 pre-fills out with b2); register double-buffered GEMM staging.
//   105.4 -> 98.6us.
// R8 (this round): top-5 = 2x 41us harness 268MB workspace-poison fills =>
//   ~82us harness floor; our 3 kernels ~16.6us. K=256 fits entirely in LDS
//   (gemm1 37KB, gemm2 53KB), so stage ALL K up front and run ONE
//   __syncthreads instead of 16 -- kills barrier serialization at 2 waves/CU.
//   Staging keeps the proven per-tile write mapping (2-way LDS conflict,
//   free; a flat full-row remap would be 16-way on ds_write -- checked).

typedef _Float16 h2 __attribute__((ext_vector_type(2)));
typedef _Float16 h4 __attribute__((ext_vector_type(4)));
typedef _Float16 h8 __attribute__((ext_vector_type(8)));

// ---------------------------------------------------------------------------
// GEMM-NT stage 1: Xp = X @ W_sr.T (and Y-path), f32 in -> f16 LDS, dot2,
// f16 out. M=512, N=256, K=256, lda=ldb=256. BM=32, BN=32, full K in LDS.
// 128 threads, per-thread 4 rows x 2 cols. LDS pair-major [kp][2m],
// stride 72 halfs. Single barrier. Also pre-fills out with b2.
// ---------------------------------------------------------------------------
__global__ __launch_bounds__(128) void gemm1_f16(
    const float* __restrict__ A0, const float* __restrict__ A1,
    const float* __restrict__ B0, const float* __restrict__ B1,
    _Float16* __restrict__ C0, _Float16* __restrict__ C1,
    const float* __restrict__ b2, float* __restrict__ out)
{
    const int z = blockIdx.z;
    const float* A = z ? A1 : A0;
    const float* B = z ? B1 : B0;
    _Float16* Cc   = z ? C1 : C0;

    __shared__ _Float16 As2[128 * 72];   // [kp=0..127][2m], 64 halfs used/row
    __shared__ _Float16 Bs2[128 * 72];   // [kp][2n]

    const int t  = threadIdx.x;
    const int m0 = blockIdx.x * 32;
    const int n0 = blockIdx.y * 32;
    const int ti = t >> 4;   // 0..7  -> rows 4ti..4ti+3
    const int tj = t & 15;   // 0..15 -> cols 2tj..2tj+1

    // out <- b2 (1024 floats per block; 8 per thread). Stream-ordered
    // before affinity_core's atomicAdd epilogue; re-runs on every graph
    // replay so the accumulation stays idempotent.
    {
        const int bid = blockIdx.x + 16 * (blockIdx.y + 8 * blockIdx.z);
        const float bb = b2[0];
        float4 f = {bb, bb, bb, bb};
        float* o = out + bid * 1024 + t * 8;
        *(float4*)o = f;
        *(float4*)(o + 4) = f;
    }

    // Stage ALL of K: 8 virtual k-tiles, proven per-tile mapping.
    #pragma unroll 4
    for (int r = 0; r < 8; r++) {
        const int kt = r * 32;
        #pragma unroll
        for (int s = 0; s < 2; s++) {
            const int id  = t + s * 128;
            const int m   = id >> 3;         // 0..31
            const int k4  = (id & 7) * 4;    // 0..28
            const int kp0 = r * 16 + (k4 >> 1);
            float4 va = *(const float4*)&A[(m0 + m) * 256 + kt + k4];
            h2 alo = {(_Float16)va.x, (_Float16)va.y};
            h2 ahi = {(_Float16)va.z, (_Float16)va.w};
            *(h2*)&As2[kp0 * 72 + 2 * m]       = alo;
            *(h2*)&As2[(kp0 + 1) * 72 + 2 * m] = ahi;
            float4 vb = *(const float4*)&B[(n0 + m) * 256 + kt + k4];
            h2 blo = {(_Float16)vb.x, (_Float16)vb.y};
            h2 bhi = {(_Float16)vb.z, (_Float16)vb.w};
            *(h2*)&Bs2[kp0 * 72 + 2 * m]       = blo;
            *(h2*)&Bs2[(kp0 + 1) * 72 + 2 * m] = bhi;
        }
    }
    __syncthreads();

    float acc[4][2] = {};
    #pragma unroll 8
    for (int kp = 0; kp < 128; kp++) {
        h8 a = *(const h8*)&As2[kp * 72 + 8 * ti];   // rows 4ti..4ti+3
        h4 b = *(const h4*)&Bs2[kp * 72 + 4 * tj];   // cols 2tj..2tj+1
        const h2* ap = (const h2*)&a;
        const h2* bp = (const h2*)&b;
        #pragma unroll
        for (int mi = 0; mi < 4; mi++)
            #pragma unroll
            for (int nj = 0; nj < 2; nj++)
                acc[mi][nj] = __builtin_amdgcn_fdot2(ap[mi], bp[nj],
                                                     acc[mi][nj], false);
    }

    #pragma unroll
    for (int mi = 0; mi < 4; mi++) {
        const int m = m0 + 4 * ti + mi;
        h2 r = {(_Float16)acc[mi][0], (_Float16)acc[mi][1]};
        *(h2*)&Cc[m * 256 + n0 + 2 * tj] = r;
    }
}

// ---------------------------------------------------------------------------
// GEMM-NT stage 2: hx = Xp @ W1x.T (+bias on y-path). A f16 (lda=256),
// B f32 (ldb=512, col offset prob*256) -> f16 LDS. M=512, N=512.
// BM=32, BN=64, full K in LDS (53KB). 128 threads, per-thread 4x4.
// As2 stride 72 halfs, Bs2 stride 136 halfs. Single barrier.
// ---------------------------------------------------------------------------
__global__ __launch_bounds__(128) void gemm2_f16(
    const _Float16* __restrict__ A0, const _Float16* __restrict__ A1,
    const float* __restrict__ B0, const float* __restrict__ B1,
    _Float16* __restrict__ C0, _Float16* __restrict__ C1,
    const float* __restrict__ bias1)
{
    const int z = blockIdx.z;
    const _Float16* A = z ? A1 : A0;
    const float* B    = z ? B1 : B0;
    _Float16* Cc      = z ? C1 : C0;
    const float* bias = z ? bias1 : nullptr;

    __shared__ _Float16 As2[128 * 72];    // [kp][2m], 64 halfs used
    __shared__ _Float16 Bs2[128 * 136];   // [kp][2n], 128 halfs used

    const int t  = threadIdx.x;
    const int m0 = blockIdx.x * 32;
    const int n0 = blockIdx.y * 64;
    const int ti = t >> 4;   // 0..7  -> rows 4ti..4ti+3
    const int tj = t & 15;   // 0..15 -> cols 4tj..4tj+3

    // Stage ALL of K.
    #pragma unroll 4
    for (int r = 0; r < 8; r++) {
        const int kt = r * 32;
        // A: 32m x 32k f16, 1 h8 per thread per tile
        {
            const int m   = t >> 2;          // 0..31
            const int k8  = (t & 3) * 8;     // 0..24
            const int kp0 = r * 16 + (k8 >> 1);
            h8 v = *(const h8*)&A[(m0 + m) * 256 + kt + k8];
            #pragma unroll
            for (int i = 0; i < 4; i++) {
                h2 p = {v[2 * i], v[2 * i + 1]};
                *(h2*)&As2[(kp0 + i) * 72 + 2 * m] = p;
            }
        }
        // B: 64n x 32k f32 -> f16, 4 float4 per thread per tile
        #pragma unroll
        for (int s = 0; s < 4; s++) {
            const int id  = t + s * 128;
            const int n   = id >> 3;         // 0..63
            const int k4  = (id & 7) * 4;
            const int kp0 = r * 16 + (k4 >> 1);
            float4 v = *(const float4*)&B[(n0 + n) * 512 + kt + k4];
            h2 lo = {(_Float16)v.x, (_Float16)v.y};
            h2 hi = {(_Float16)v.z, (_Float16)v.w};
            *(h2*)&Bs2[kp0 * 136 + 2 * n]       = lo;
            *(h2*)&Bs2[(kp0 + 1) * 136 + 2 * n] = hi;
        }
    }
    __syncthreads();

    float acc[4][4] = {};
    #pragma unroll 8
    for (int kp = 0; kp < 128; kp++) {
        h8 a = *(const h8*)&As2[kp * 72 + 8 * ti];
        h8 b = *(const h8*)&Bs2[kp * 136 + 8 * tj];
        const h2* ap = (const h2*)&a;
        const h2* bp = (const h2*)&b;
        #pragma unroll
        for (int mi = 0; mi < 4; mi++)
            #pragma unroll
            for (int nj = 0; nj < 4; nj++)
                acc[mi][nj] = __builtin_amdgcn_fdot2(ap[mi], bp[nj],
                                                     acc[mi][nj], false);
    }

    float4 bv = {0.f, 0.f, 0.f, 0.f};
    if (bias) bv = *(const float4*)&bias[n0 + 4 * tj];
    #pragma unroll
    for (int mi = 0; mi < 4; mi++) {
        const int m = m0 + 4 * ti + mi;
        h4 r = {(_Float16)(acc[mi][0] + bv.x), (_Float16)(acc[mi][1] + bv.y),
                (_Float16)(acc[mi][2] + bv.z), (_Float16)(acc[mi][3] + bv.w)};
        *(h4*)&Cc[m * 512 + n0 + 4 * tj] = r;
    }
}

// ---------------------------------------------------------------------------
// Core: out[i,j] += sum_{h in 64-slab s} relu(hx[i,h]+hy[j,h])*w2[h]
// grid (8,8,8) = 512 blocks (2/CU), 256 threads, 4x4 register tile.
// f16 operands, v_dot2_f32_f16 accumulate. f32 atomicAdd epilogue into
// out (pre-filled with b2 by gemm1).
// (proven R4/R5 body -- LDS ~6.9K cy vs VALU ~6.1K cy per CU, balanced)
// ---------------------------------------------------------------------------
__global__ __launch_bounds__(256) void affinity_core(
    const _Float16* __restrict__ hx, const _Float16* __restrict__ hy,
    const float* __restrict__ w2, float* __restrict__ out)
{
    __shared__ __align__(16) _Float16 xs[64 * 72];
    __shared__ __align__(16) _Float16 ys[64 * 72];
    __shared__ __align__(16) _Float16 ws2[64];

    const int t  = threadIdx.x;
    const int i0 = blockIdx.x * 64;
    const int j0 = blockIdx.y * 64;
    const int h0 = blockIdx.z * 64;
    const int ti = t / 16;
    const int tj = t % 16;

    #pragma unroll
    for (int s = 0; s < 2; s++) {
        const int id = t + s * 256;
        const int r  = id >> 3;
        const int c8 = (id & 7) * 8;
        *(float4*)&xs[r * 72 + c8] = *(const float4*)&hx[(i0 + r) * 512 + h0 + c8];
        *(float4*)&ys[r * 72 + c8] = *(const float4*)&hy[(j0 + r) * 512 + h0 + c8];
    }
    if (t < 64) ws2[t] = (_Float16)w2[h0 + t];
    __syncthreads();

    float acc[4][4] = {};
    const _Float16* xr = xs + ti * 72;
    const _Float16* yr = ys + tj * 72;
    const h2 hz = {(_Float16)0.f, (_Float16)0.f};

    #pragma unroll 2
    for (int g = 0; g < 8; g++) {
        const int ho = g * 8;
        h8 w = *(const h8*)&ws2[ho];
        h8 x[4], y[4];
        #pragma unroll
        for (int m = 0; m < 4; m++) x[m] = *(const h8*)&xr[m * (16 * 72) + ho];
        #pragma unroll
        for (int n = 0; n < 4; n++) y[n] = *(const h8*)&yr[n * (16 * 72) + ho];
        const h2* wp = (const h2*)&w;
        #pragma unroll
        for (int m = 0; m < 4; m++) {
            const h2* xp = (const h2*)&x[m];
            #pragma unroll
            for (int n = 0; n < 4; n++) {
                const h2* yp = (const h2*)&y[n];
                float a = acc[m][n];
                #pragma unroll
                for (int p = 0; p < 4; p++) {
                    h2 s = xp[p] + yp[p];                           // v_pk_add_f16
                    s = __builtin_elementwise_max(s, hz);           // v_pk_max_f16
                    a = __builtin_amdgcn_fdot2(s, wp[p], a, false); // v_dot2_f32_f16
                }
                acc[m][n] = a;
            }
        }
    }

    // Atomic f32 epilogue: 8-way contention per address (one per h-slab),
    // 2M atomics total -- well within L2 atomic throughput.
    #pragma unroll
    for (int m = 0; m < 4; m++) {
        #pragma unroll
        for (int n = 0; n < 4; n++) {
            atomicAdd(&out[(i0 + ti + 16 * m) * 512 + (j0 + tj + 16 * n)],
                      acc[m][n]);
        }
    }
}

extern "C" void kernel_launch(void* const* d_in, const int* in_sizes, int n_in,
                              void* d_out, int out_size, void* d_ws, size_t ws_size,
                              hipStream_t stream) {
    const float* X    = (const float*)d_in[0];  // 512x256
    const float* Y    = (const float*)d_in[1];  // 512x256
    const float* W_sr = (const float*)d_in[2];  // 256x256
    const float* W_tg = (const float*)d_in[3];  // 256x256
    const float* W1   = (const float*)d_in[4];  // 512x512 (H x 2C)
    const float* b1   = (const float*)d_in[5];  // 512
    const float* w2   = (const float*)d_in[6];  // 1x512
    const float* b2   = (const float*)d_in[7];  // 1

    float* ws = (float*)d_ws;
    _Float16* Xp = (_Float16*)ws;               // 512x256 f16
    _Float16* Yp = (_Float16*)(ws + 65536);     // 512x256 f16
    _Float16* hx = (_Float16*)(ws + 131072);    // 512x512 f16
    _Float16* hy = (_Float16*)(ws + 262144);    // 512x512 f16
    float* out = (float*)d_out;

    // Stage 1: Xp = X @ W_sr.T ; Yp = Y @ W_tg.T ; out <- b2
    gemm1_f16<<<dim3(16, 8, 2), 128, 0, stream>>>(
        X, Y, W_sr, W_tg, Xp, Yp, b2, out);
    // Stage 2: hx = Xp @ W1x.T ; hy = Yp @ W1y.T + b1
    gemm2_f16<<<dim3(16, 8, 2), 128, 0, stream>>>(
        Xp, Yp, W1, W1 + 256, hx, hy, b1);
    // Stage 3: h-split relu reduction, atomic f32 accumulate into out
    affinity_core<<<dim3(8, 8, 8), 256, 0, stream>>>(hx, hy, w2, out);
}